// Round 1
// baseline (765.239 us; speedup 1.0000x reference)
//
#include <hip/hip_runtime.h>
#include <stdint.h>

#define IN_DIM 32768
#define CLASSES 100
#define BATCH 4096
#define NPAD 112              // 7 x 16 MFMA n-tiles
#define BK 32
#define MTILE 128
#define SPLITK 16
#define KCHUNK (IN_DIM / SPLITK)   // 2048
#define NSTEP (KCHUNK / BK)        // 64
#define MBLOCKS (BATCH / MTILE)    // 32
#define WTILE_ELEMS (NPAD * BK)    // 3584 shorts = 7168 B per k-step tile

typedef __attribute__((ext_vector_type(8))) short short8;
typedef __attribute__((ext_vector_type(4))) float floatx4;
typedef __attribute__((ext_vector_type(4))) uint32_t uintx4;

// fp32 -> bf16 round-to-nearest-even (bit trick; inputs are finite normals)
__device__ inline uint32_t f2bf(float f) {
  union { float f; uint32_t u; } v; v.f = f;
  uint32_t u = v.u;
  u += 0x7FFFu + ((u >> 16) & 1u);
  return u >> 16;
}
__device__ inline uint32_t pk(float a, float b) {
  return f2bf(a) | (f2bf(b) << 16);
}

// async 16B global->LDS DMA (wave-uniform base + lane*16 semantics)
__device__ inline void async_cp16(const void* g, void* l) {
  __builtin_amdgcn_global_load_lds(
      (const __attribute__((address_space(1))) uint32_t*)g,
      (__attribute__((address_space(3))) uint32_t*)l,
      16, 0, 0);
}

// Pack sign(W) as bf16 {+1,-1,0} into ws, pre-swizzled into MFMA B-fragment
// tile order: [kstep][ntile][kq][n][j]  (ntile=c>>4, n=c&15, kq=(k>>3)&3, j=k&7)
// so the GEMM stages each 7168B k-step tile with linear global_load_lds and
// reads B-frags as ds_read_b128 at (ntile*1024 + lane*16)  -> conflict-free.
__global__ void pack_w_kernel(const float* __restrict__ W, short* __restrict__ wp) {
  int idx = blockIdx.x * 256 + threadIdx.x;      // [0, NPAD*IN_DIM)
  int c = idx >> 15;
  int kg = idx & (IN_DIM - 1);
  short val = 0;
  if (c < CLASSES) {
    float w = W[((size_t)c << 15) + kg];
    val = (w > 0.0f) ? (short)0x3F80 : ((w < 0.0f) ? (short)0xBF80 : (short)0);
  }
  int kstep = kg >> 5;
  int rem = kg & 31;
  int kq = rem >> 3;
  int j = rem & 7;
  int nt = c >> 4;
  int n = c & 15;
  wp[(size_t)kstep * WTILE_ELEMS + nt * 512 + kq * 128 + n * 8 + j] = val;
}

// GEMM: out[m][c] += sum_k x[m][k] * signW[c][k] * scale
// block: 256 threads (4 waves). tile: 128 rows x 112 cols, BK=32, 64 k-steps.
// wave w handles rows [w*32, w*32+32) = m-groups {2w, 2w+1}, all 7 n-tiles.
__global__ __launch_bounds__(256, 2) void gemm_kernel(const float* __restrict__ x,
                                                      const short* __restrict__ wp,
                                                      float* __restrict__ out) {
  // layouts: [group][kq][n][j] bf16; one group = 512 shorts = 1024 B
  __shared__ __align__(16) short xlds[MTILE * BK];   // 4096 shorts = 8 KiB
  __shared__ __align__(16) short wlds[WTILE_ELEMS];  // 3584 shorts = 7 KiB

  const int tid = threadIdx.x;
  const int lane = tid & 63;
  const int w = tid >> 6;
  const int mb = blockIdx.x & (MBLOCKS - 1);
  const int ks = blockIdx.x >> 5;           // split-K index
  const int m_base = mb * MTILE;
  const int k0 = ks * KCHUNK;

  floatx4 acc[2][7];
#pragma unroll
  for (int i = 0; i < 2; ++i)
#pragma unroll
    for (int j = 0; j < 7; ++j) acc[i][j] = (floatx4)0.0f;

  // x staging assignment: thread -> (row_l = tid>>1, khalf = tid&1), 16 floats
  const int row_l = tid >> 1;
  const int khalf = tid & 1;
  const float* xrow = x + (size_t)(m_base + row_l) * IN_DIM + k0 + khalf * 16;
  const int mg = row_l >> 4;
  const int nn = row_l & 15;
  uint32_t* xdst0 = (uint32_t*)&xlds[mg * 512 + (khalf * 2) * 128 + nn * 8];
  uint32_t* xdst1 = xdst0 + 64;   // next kq block (+128 shorts)

  const short8* xa = (const short8*)xlds;
  const short8* wb = (const short8*)wlds;

  for (int t = 0; t < NSTEP; ++t) {
    if (t) __syncthreads();          // previous compute done reading LDS

    // --- stage W tile (async DMA, pre-swizzled source) ---
    const short* wsrc = wp + (size_t)(ks * NSTEP + t) * WTILE_ELEMS;
    async_cp16(wsrc + tid * 8, &wlds[tid * 8]);
    if (tid < 192)                   // 448 chunks total; waves 0-2 fully active
      async_cp16(wsrc + (256 + tid) * 8, &wlds[(256 + tid) * 8]);

    // --- stage x tile (load fp32, cvt bf16, ds_write_b128) ---
    const float* xp = xrow + t * BK;
    floatx4 f0 = *(const floatx4*)(xp);
    floatx4 f1 = *(const floatx4*)(xp + 4);
    floatx4 f2 = *(const floatx4*)(xp + 8);
    floatx4 f3 = *(const floatx4*)(xp + 12);
    uintx4 p0 = { pk(f0.x, f0.y), pk(f0.z, f0.w), pk(f1.x, f1.y), pk(f1.z, f1.w) };
    uintx4 p1 = { pk(f2.x, f2.y), pk(f2.z, f2.w), pk(f3.x, f3.y), pk(f3.z, f3.w) };
    *(uintx4*)xdst0 = p0;
    *(uintx4*)xdst1 = p1;

    __syncthreads();                 // staging (incl. async DMA) complete

    // --- compute: 2 A-frags, 7 B-frags, 14 MFMAs per wave ---
    short8 a0 = xa[(2 * w) * 64 + lane];       // byte addr = mg*1024 + lane*16
    short8 a1 = xa[(2 * w + 1) * 64 + lane];
#pragma unroll
    for (int nt = 0; nt < 7; ++nt) {
      short8 b = wb[nt * 64 + lane];           // byte addr = nt*1024 + lane*16
      acc[0][nt] = __builtin_amdgcn_mfma_f32_16x16x32_bf16(a0, b, acc[0][nt], 0, 0, 0);
      acc[1][nt] = __builtin_amdgcn_mfma_f32_16x16x32_bf16(a1, b, acc[1][nt], 0, 0, 0);
    }
  }

  // --- epilogue: scale + atomic split-K reduction into d_out ---
  const float scale = 0.005524271728019903f;   // 1/sqrt(32768)
  const int quad = lane >> 4;
  const int n16 = lane & 15;
#pragma unroll
  for (int mgi = 0; mgi < 2; ++mgi) {
    int row0 = m_base + w * 32 + mgi * 16 + quad * 4;
#pragma unroll
    for (int nt = 0; nt < 7; ++nt) {
      int col = nt * 16 + n16;
      if (col < CLASSES) {
#pragma unroll
        for (int r = 0; r < 4; ++r)
          atomicAdd(&out[(size_t)(row0 + r) * CLASSES + col], acc[mgi][nt][r] * scale);
      }
    }
  }
}

extern "C" void kernel_launch(void* const* d_in, const int* in_sizes, int n_in,
                              void* d_out, int out_size, void* d_ws, size_t ws_size,
                              hipStream_t stream) {
  const float* x = (const float*)d_in[0];   // [4096, 32768] fp32
  const float* W = (const float*)d_in[1];   // [100, 32768] fp32
  float* out = (float*)d_out;               // [4096, 100] fp32
  short* wp = (short*)d_ws;                 // packed sign(W) bf16, 7.34 MB

  hipMemsetAsync(d_out, 0, (size_t)BATCH * CLASSES * sizeof(float), stream);
  pack_w_kernel<<<(NPAD * IN_DIM) / 256, 256, 0, stream>>>(W, wp);
  gemm_kernel<<<MBLOCKS * SPLITK, 256, 0, stream>>>(x, wp, out);
}

// Round 2
// 745.804 us; speedup vs baseline: 1.0261x; 1.0261x over previous
//
#include <hip/hip_runtime.h>
#include <stdint.h>

#define IN_DIM 32768
#define CLASSES 100
#define BATCH 4096
#define NPAD 112                   // 7 x 16 MFMA n-tiles
#define BK 32
#define MTILE 64
#define SPLITK 16
#define KCHUNK (IN_DIM / SPLITK)   // 2048
#define NSTEP (KCHUNK / BK)        // 64
#define MBLOCKS (BATCH / MTILE)    // 64
#define WTILE_ELEMS (NPAD * BK)    // 3584 shorts = 7168 B per k-step tile
#define NTILES (SPLITK * NSTEP)    // 1024 tiles total in wp
#define WP_ELEMS (NPAD * IN_DIM)   // 3,670,016 shorts = 7.34 MB
#define PART_STRIDE (BATCH * NPAD) // floats per split-K slice
#define PART_OFF_BYTES (8u << 20)  // partials start 8 MB into ws (wp ends at 7.34 MB)

typedef __attribute__((ext_vector_type(8))) short short8;
typedef __attribute__((ext_vector_type(4))) float floatx4;

// fp32 -> bf16 round-to-nearest-even (bit trick; inputs are finite normals)
__device__ inline uint32_t f2bf(float f) {
  union { float f; uint32_t u; } v; v.f = f;
  uint32_t u = v.u;
  u += 0x7FFFu + ((u >> 16) & 1u);
  return u >> 16;
}
__device__ inline uint32_t pk(float a, float b) {
  return f2bf(a) | (f2bf(b) << 16);
}

// async 16B global->LDS DMA (wave-uniform base + lane*16 semantics)
__device__ inline void async_cp16(const void* g, void* l) {
  __builtin_amdgcn_global_load_lds(
      (const __attribute__((address_space(1))) uint32_t*)g,
      (__attribute__((address_space(3))) uint32_t*)l,
      16, 0, 0);
}

// Pack sign(W) as bf16 {+1,-1,0} into wp, pre-swizzled into MFMA B-fragment
// tile order: [kstep][ntile][kq][n][j] (ntile=c>>4, n=c&15, kq=(k>>3)&3, j=k&7)
// -> GEMM stages each 7168B tile with linear global_load_lds; B-frag reads are
// ds_read_b128 at (ntile*1024 + lane*16) -> conflict-free. (validated in R1)
__global__ void pack_w_kernel(const float* __restrict__ W, short* __restrict__ wp) {
  int idx = blockIdx.x * 256 + threadIdx.x;      // [0, NPAD*IN_DIM)
  int c = idx >> 15;
  int kg = idx & (IN_DIM - 1);
  short val = 0;
  if (c < CLASSES) {
    float w = W[((size_t)c << 15) + kg];
    val = (w > 0.0f) ? (short)0x3F80 : ((w < 0.0f) ? (short)0xBF80 : (short)0);
  }
  int kstep = kg >> 5;
  int rem = kg & 31;
  int kq = rem >> 3;
  int j = rem & 7;
  int nt = c >> 4;
  int n = c & 15;
  wp[(size_t)kstep * WTILE_ELEMS + nt * 512 + kq * 128 + n * 8 + j] = val;
}

// GEMM: part[ks][m][c] = sum_{k in chunk ks} x[m][k] * signW[c][k]
// 1024 blocks (64 m-blocks x 16 split-K), 256 threads (4 waves), 4 blocks/CU.
// Wave w owns rows [m_base + 16w, +16): A-frags loaded DIRECTLY from global
// (lane l -> row lane&15, k quad*8+j; each 128B line consumed by 4 lanes of one
// instruction), cvt to bf16 in-register. W via double-buffered global_load_lds
// issued one iteration ahead so the barrier's vmcnt drain is cheap.
__global__ __launch_bounds__(256, 4) void gemm_kernel(const float* __restrict__ x,
                                                      const short* __restrict__ wp,
                                                      float* __restrict__ part) {
  __shared__ __align__(16) short wlds[2][WTILE_ELEMS];   // 2 x 7 KiB

  const int tid = threadIdx.x;
  const int lane = tid & 63;
  const int w = tid >> 6;
  const int mb = blockIdx.x & (MBLOCKS - 1);
  const int ks = blockIdx.x >> 6;           // split-K index
  const int m_base = mb * MTILE;
  const int quad = lane >> 4;

  // A-source pointer for this lane: its row, its k-quad, within this K-chunk
  const float* xp = x + (size_t)(m_base + w * 16 + (lane & 15)) * IN_DIM
                      + ks * KCHUNK + quad * 8;

  floatx4 acc[7];
#pragma unroll
  for (int n = 0; n < 7; ++n) acc[n] = (floatx4)0.0f;

  // ---- prologue: DMA W tile 0, prefetch x tile 0 ----
  {
    const short* ws0 = wp + (size_t)(ks * NSTEP) * WTILE_ELEMS;
    async_cp16(ws0 + tid * 8, &wlds[0][tid * 8]);
    if (tid < 192)
      async_cp16(ws0 + (256 + tid) * 8, &wlds[0][(256 + tid) * 8]);
  }
  floatx4 g0 = *(const floatx4*)xp;
  floatx4 g1 = *(const floatx4*)(xp + 4);

  for (int t = 0; t < NSTEP; ++t) {
    __syncthreads();   // drains DMA W(t) (issued one iter ago) + x regs (t)

    // --- issue DMA for W tile t+1 into the other buffer ---
    int tile = ks * NSTEP + t + 1;
    if (tile > NTILES - 1) tile = NTILES - 1;          // clamp (dead on last)
    const short* wsrc = wp + (size_t)tile * WTILE_ELEMS;
    short* wdst = wlds[(t + 1) & 1];
    async_cp16(wsrc + tid * 8, wdst + tid * 8);
    if (tid < 192)
      async_cp16(wsrc + (256 + tid) * 8, wdst + (256 + tid) * 8);

    // --- build A fragment from prefetched x regs (tile t) ---
    short8 a;
    uint32_t* au = (uint32_t*)&a;
    au[0] = pk(g0.x, g0.y); au[1] = pk(g0.z, g0.w);
    au[2] = pk(g1.x, g1.y); au[3] = pk(g1.z, g1.w);

    // --- issue x prefetch for tile t+1 ---
    int tn = (t + 1 < NSTEP) ? t + 1 : 0;              // dead on last iter
    const float* xn = xp + tn * BK;
    g0 = *(const floatx4*)xn;
    g1 = *(const floatx4*)(xn + 4);

    // --- compute: 7 B-frags, 7 MFMAs ---
    const short8* wb = (const short8*)wlds[t & 1];
#pragma unroll
    for (int n = 0; n < 7; ++n) {
      short8 b = wb[n * 64 + lane];                    // nt*1024B + lane*16B
      acc[n] = __builtin_amdgcn_mfma_f32_16x16x32_bf16(a, b, acc[n], 0, 0, 0);
    }
  }

  // ---- epilogue: plain stores of partials (no atomics) ----
  // C layout: col = lane&15, row = quad*4 + r
  float* pr = part + (size_t)ks * PART_STRIDE;
  const int r0 = m_base + w * 16 + quad * 4;
  const int c16 = lane & 15;
#pragma unroll
  for (int n = 0; n < 7; ++n) {
    int col = n * 16 + c16;
#pragma unroll
    for (int r = 0; r < 4; ++r)
      pr[(size_t)(r0 + r) * NPAD + col] = acc[n][r];
  }
}

// out[b][c] = scale * sum_ks part[ks][b][c]
__global__ void reduce_kernel(const float* __restrict__ part, float* __restrict__ out) {
  int b = blockIdx.x;
  int c = threadIdx.x;
  if (c >= CLASSES) return;
  const float* p = part + (size_t)b * NPAD + c;
  float s = 0.0f;
#pragma unroll
  for (int ks = 0; ks < SPLITK; ++ks) s += p[(size_t)ks * PART_STRIDE];
  out[(size_t)b * CLASSES + c] = s * 0.005524271728019903f;   // 1/sqrt(32768)
}

extern "C" void kernel_launch(void* const* d_in, const int* in_sizes, int n_in,
                              void* d_out, int out_size, void* d_ws, size_t ws_size,
                              hipStream_t stream) {
  const float* x = (const float*)d_in[0];   // [4096, 32768] fp32
  const float* W = (const float*)d_in[1];   // [100, 32768] fp32
  float* out = (float*)d_out;               // [4096, 100] fp32
  short* wp = (short*)d_ws;                 // packed sign(W), 7.34 MB
  float* part = (float*)((char*)d_ws + PART_OFF_BYTES);  // 29.4 MB partials

  pack_w_kernel<<<WP_ELEMS / 256, 256, 0, stream>>>(W, wp);
  gemm_kernel<<<MBLOCKS * SPLITK, 256, 0, stream>>>(x, wp, part);
  reduce_kernel<<<BATCH, 128, 0, stream>>>(part, out);
}